// Round 10
// baseline (202.064 us; speedup 1.0000x reference)
//
#include <hip/hip_runtime.h>
#include <hip/hip_bf16.h>
#include <math.h>

#define N_ROWS 4096
#define D_DIM  128
#define M_ROWS 8192
#define INV_T  10.0f
// sqrt(10/ln2): zn scaled so Gram(zn) = 10*log2(e)*cos  =>  exp2(Gram) = e^(10*cos)
#define BF_SCALE 3.79828218f
#define NTAIL 2080   // blocks that reach the fused tail (33*64 - 32 early-outs)

#if __has_builtin(__builtin_amdgcn_exp2f)
#define EXP2(x) __builtin_amdgcn_exp2f(x)   // bare v_exp_f32, no OCML fixup
#else
#define EXP2(x) exp2f(x)
#endif

typedef __attribute__((ext_vector_type(8))) short bf16x8;
typedef __attribute__((ext_vector_type(4))) float f32x4;

// --- Kernel 1: fused normalize (scaled bf16) + pos + zero S + zero done ---
__global__ __launch_bounds__(256) void prep_kernel(
    const float* __restrict__ z1, const float* __restrict__ z2,
    ushort* __restrict__ zn, float* __restrict__ pos,
    float* __restrict__ S, unsigned* __restrict__ done)
{
    if (blockIdx.x < 32) S[blockIdx.x * 256 + threadIdx.x] = 0.f;
    if (blockIdx.x == 32 && threadIdx.x == 0) *done = 0u;

    const int i    = blockIdx.x * 4 + (threadIdx.x >> 6);
    const int lane = threadIdx.x & 63;
    float2 a = ((const float2*)(z1 + (size_t)i * D_DIM))[lane];
    float2 b = ((const float2*)(z2 + (size_t)i * D_DIM))[lane];
    float s11 = a.x * a.x + a.y * a.y;
    float s22 = b.x * b.x + b.y * b.y;
    float s12 = a.x * b.x + a.y * b.y;
    #pragma unroll
    for (int m = 1; m < 64; m <<= 1) {
        s11 += __shfl_xor(s11, m, 64);
        s22 += __shfl_xor(s22, m, 64);
        s12 += __shfl_xor(s12, m, 64);
    }
    float inv1 = 1.0f / fmaxf(sqrtf(s11), 1e-8f);
    float inv2 = 1.0f / fmaxf(sqrtf(s22), 1e-8f);
    if (lane == 0) pos[i] = 2.0f * INV_T * s12 * inv1 * inv2;
    const float sa = inv1 * BF_SCALE, sb = inv2 * BF_SCALE;
    __hip_bfloat16 h;
    ushort2 oa, ob;
    h = __float2bfloat16(a.x * sa); oa.x = *(const ushort*)&h;
    h = __float2bfloat16(a.y * sa); oa.y = *(const ushort*)&h;
    h = __float2bfloat16(b.x * sb); ob.x = *(const ushort*)&h;
    h = __float2bfloat16(b.y * sb); ob.y = *(const ushort*)&h;
    ((ushort2*)zn)[(size_t)i * 64 + lane] = oa;
    ((ushort2*)zn)[(size_t)(i + N_ROWS) * 64 + lane] = ob;
}

// --- Kernel 2: symmetric simsum, single-barrier staging + fused loss tail ---
// Upper triangle of 128x128 unit tiles only (E symmetric). Wrapped-diagonal
// grid: (bx,rU) in 33x64, cU=(rU+bx)&63, bx==32 only for rU<32 (2080 blocks).
// Whole 128-col B tile staged once into 32 KiB LDS (XOR-swizzled), ONE
// barrier, then 8 independent col-tiles of MFMA+exp per wave. Off-diagonal
// blocks scatter row sums AND column sums. Last block computes the loss.
__global__ __launch_bounds__(256) void simsum_kernel(
    const short* __restrict__ zn, float* __restrict__ S,
    const float* __restrict__ pos, float* __restrict__ out,
    unsigned* __restrict__ done)
{
    const int bx = blockIdx.x;          // 0..32
    const int rU = blockIdx.y;          // 0..63
    if (bx == 32 && rU >= 32) return;   // distance-32 pairs covered once
    const int cU = (rU + bx) & 63;
    const bool isDiag = (bx == 0);

    __shared__ uint4 lbuf[128 * 16];    // 32 KiB: [row][chunk], XOR-swizzled
    __shared__ float colpart[4][128];

    const int tid  = threadIdx.x;
    const int lane = tid & 63;
    const int w    = tid >> 6;
    const int m    = lane & 15;
    const int q    = lane >> 4;
    const int rowBase = rU * 128 + w * 32;
    const int colBase = cU * 128;

    // A fragments: 2 row-sets x 4 K-steps, registers for the whole kernel
    bf16x8 afrag[2][4];
    #pragma unroll
    for (int h = 0; h < 2; ++h) {
        const short* ar = zn + (size_t)(rowBase + h * 16 + m) * D_DIM + q * 8;
        #pragma unroll
        for (int s = 0; s < 4; ++s) afrag[h][s] = *(const bf16x8*)(ar + s * 32);
    }

    // Stage the whole 128 x 256B col tile: 8 uint4 per thread, coalesced.
    // Rows sr+16j => row&15 == sr, so swizzled chunk sc^sr is constant.
    {
        const int sr = tid >> 4;
        const int sc = tid & 15;
        const uint4* gsrc = (const uint4*)(zn + (size_t)(colBase + sr) * D_DIM) + sc;
        const int swc = sc ^ sr;
        uint4 regs[8];
        #pragma unroll
        for (int j = 0; j < 8; ++j) regs[j] = gsrc[j * 256];   // 16 rows apart
        #pragma unroll
        for (int j = 0; j < 8; ++j) lbuf[(sr + j * 16) * 16 + swc] = regs[j];
    }

    __syncthreads();   // the only staging barrier

    float rsum[8] = {0.f, 0.f, 0.f, 0.f, 0.f, 0.f, 0.f, 0.f};
    const short* lb = (const short*)lbuf;

    #pragma unroll 2
    for (int ct = 0; ct < 8; ++ct) {
        f32x4 acc0 = {0.f, 0.f, 0.f, 0.f};
        f32x4 acc1 = {0.f, 0.f, 0.f, 0.f};
        #pragma unroll
        for (int s = 0; s < 4; ++s) {
            bf16x8 bfrag = *(const bf16x8*)(lb + (ct * 16 + m) * D_DIM
                                            + (((q + s * 4) ^ m) * 8));
            acc0 = __builtin_amdgcn_mfma_f32_16x16x32_bf16(afrag[0][s], bfrag, acc0, 0, 0, 0);
            acc1 = __builtin_amdgcn_mfma_f32_16x16x32_bf16(afrag[1][s], bfrag, acc1, 0, 0, 0);
        }
        const int tileCol = colBase + ct * 16;
        float e0[4], e1[4];
        #pragma unroll
        for (int r = 0; r < 4; ++r) { e0[r] = EXP2(acc0[r]); e1[r] = EXP2(acc1[r]); }
        // diagonal mask: wave-uniform branches; fire only when rU == cU
        if (tileCol == rowBase) {
            #pragma unroll
            for (int r = 0; r < 4; ++r) if (m == q * 4 + r) e0[r] = 0.f;
        }
        if (tileCol == rowBase + 16) {
            #pragma unroll
            for (int r = 0; r < 4; ++r) if (m == q * 4 + r) e1[r] = 0.f;
        }
        #pragma unroll
        for (int r = 0; r < 4; ++r) { rsum[r] += e0[r]; rsum[4 + r] += e1[r]; }
        // column partial for col (tileCol + m): sum this wave's 32 rows
        float cs = (e0[0] + e0[1]) + (e0[2] + e0[3])
                 + (e1[0] + e1[1]) + (e1[2] + e1[3]);
        cs += __shfl_xor(cs, 16, 64);
        cs += __shfl_xor(cs, 32, 64);
        if (q == 0) colpart[w][ct * 16 + m] = cs;
    }

    // row sums -> S[row]
    #pragma unroll
    for (int msk = 1; msk < 16; msk <<= 1) {
        #pragma unroll
        for (int r = 0; r < 8; ++r) rsum[r] += __shfl_xor(rsum[r], msk, 64);
    }
    if (m < 4) {
        atomicAdd(&S[rowBase + q * 4 + m],      rsum[m]);
        atomicAdd(&S[rowBase + 16 + q * 4 + m], rsum[4 + m]);
    }

    __syncthreads();   // colpart visibility across waves
    if (!isDiag && tid < 128) {
        float c = (colpart[0][tid] + colpart[1][tid])
                + (colpart[2][tid] + colpart[3][tid]);
        atomicAdd(&S[colBase + tid], c);
    }

    // ---- fused loss: last of the 2080 tail-reaching blocks reduces S ----
    __threadfence();
    __syncthreads();
    __shared__ unsigned sprev;
    if (tid == 0) sprev = atomicAdd(done, 1u);
    __syncthreads();
    if (sprev == NTAIL - 1) {
        float acc = 0.f;
        for (int i = tid; i < M_ROWS; i += 256) {
            float s = __hip_atomic_load(&S[i], __ATOMIC_RELAXED, __HIP_MEMORY_SCOPE_AGENT);
            float p = pos[i & (N_ROWS - 1)];
            acc += __logf(s + __expf(p)) - p;
        }
        #pragma unroll
        for (int msk = 1; msk < 64; msk <<= 1) acc += __shfl_xor(acc, msk, 64);
        __shared__ float red[4];
        if (lane == 0) red[w] = acc;
        __syncthreads();
        if (tid == 0)
            out[0] = (red[0] + red[1] + red[2] + red[3])
                     / ((float)M_ROWS * (float)M_ROWS);
    }
}

extern "C" void kernel_launch(void* const* d_in, const int* in_sizes, int n_in,
                              void* d_out, int out_size, void* d_ws, size_t ws_size,
                              hipStream_t stream)
{
    const float* z1 = (const float*)d_in[0];
    const float* z2 = (const float*)d_in[1];
    float* out = (float*)d_out;

    char* wsp = (char*)d_ws;
    short* zn      = (short*)(wsp);                            // 2 MiB
    float* pos     = (float*)(wsp + 2097152);                  // 16 KiB
    float* S       = (float*)(wsp + 2097152 + 16384);          // 32 KiB
    unsigned* done = (unsigned*)(wsp + 2097152 + 16384 + 32768);

    prep_kernel<<<N_ROWS / 4, 256, 0, stream>>>(z1, z2, (ushort*)zn, pos, S, done);
    simsum_kernel<<<dim3(33, 64), 256, 0, stream>>>(zn, S, pos, out, done);
}

// Round 11
// 77.673 us; speedup vs baseline: 2.6015x; 2.6015x over previous
//
#include <hip/hip_runtime.h>
#include <hip/hip_bf16.h>
#include <math.h>

#define N_ROWS 4096
#define D_DIM  128
#define M_ROWS 8192
#define INV_T  10.0f
// sqrt(10/ln2): zn scaled so Gram(zn) = 10*log2(e)*cos  =>  exp2(Gram) = e^(10*cos)
#define BF_SCALE 3.79828218f

#if __has_builtin(__builtin_amdgcn_exp2f)
#define EXP2(x) __builtin_amdgcn_exp2f(x)   // bare v_exp_f32, no OCML fixup
#else
#define EXP2(x) exp2f(x)
#endif

typedef __attribute__((ext_vector_type(8))) short bf16x8;
typedef __attribute__((ext_vector_type(4))) float f32x4;

// --- Kernel 1: fused normalize (scaled bf16) + pos + zero S + zero out ---
__global__ __launch_bounds__(256) void prep_kernel(
    const float* __restrict__ z1, const float* __restrict__ z2,
    ushort* __restrict__ zn, float* __restrict__ pos,
    float* __restrict__ S, float* __restrict__ out)
{
    if (blockIdx.x < 32) S[blockIdx.x * 256 + threadIdx.x] = 0.f;
    if (blockIdx.x == 32 && threadIdx.x == 0) out[0] = 0.f;

    const int i    = blockIdx.x * 4 + (threadIdx.x >> 6);
    const int lane = threadIdx.x & 63;
    float2 a = ((const float2*)(z1 + (size_t)i * D_DIM))[lane];
    float2 b = ((const float2*)(z2 + (size_t)i * D_DIM))[lane];
    float s11 = a.x * a.x + a.y * a.y;
    float s22 = b.x * b.x + b.y * b.y;
    float s12 = a.x * b.x + a.y * b.y;
    #pragma unroll
    for (int m = 1; m < 64; m <<= 1) {
        s11 += __shfl_xor(s11, m, 64);
        s22 += __shfl_xor(s22, m, 64);
        s12 += __shfl_xor(s12, m, 64);
    }
    float inv1 = 1.0f / fmaxf(sqrtf(s11), 1e-8f);
    float inv2 = 1.0f / fmaxf(sqrtf(s22), 1e-8f);
    if (lane == 0) pos[i] = 2.0f * INV_T * s12 * inv1 * inv2;
    const float sa = inv1 * BF_SCALE, sb = inv2 * BF_SCALE;
    __hip_bfloat16 h;
    ushort2 oa, ob;
    h = __float2bfloat16(a.x * sa); oa.x = *(const ushort*)&h;
    h = __float2bfloat16(a.y * sa); oa.y = *(const ushort*)&h;
    h = __float2bfloat16(b.x * sb); ob.x = *(const ushort*)&h;
    h = __float2bfloat16(b.y * sb); ob.y = *(const ushort*)&h;
    ((ushort2*)zn)[(size_t)i * 64 + lane] = oa;
    ((ushort2*)zn)[(size_t)(i + N_ROWS) * 64 + lane] = ob;
}

// --- Kernel 2: symmetric simsum. E = exp(sim) is symmetric: only the upper
// triangle of 128x128 unit tiles is computed. Wrapped-diagonal grid: (bx,rU)
// in 33x64, cU=(rU+bx)&63, bx==32 only for rU<32 => each unordered pair once
// (2080 blocks). Off-diagonal blocks scatter row sums AND column sums.
// One-shot staging: whole 128-col tile -> 32 KiB LDS (XOR-swizzled), ONE
// staging barrier, then 8 independent col-tiles. NO device fences anywhere.
__global__ __launch_bounds__(256) void simsum_kernel(
    const short* __restrict__ zn, float* __restrict__ S)
{
    const int bx = blockIdx.x;          // 0..32
    const int rU = blockIdx.y;          // 0..63
    if (bx == 32 && rU >= 32) return;   // distance-32 pairs covered once
    const int cU = (rU + bx) & 63;
    const bool isDiag = (bx == 0);

    __shared__ uint4 lbuf[128 * 16];    // 32 KiB: [row][chunk], XOR-swizzled
    __shared__ float colpart[4][128];

    const int tid  = threadIdx.x;
    const int lane = tid & 63;
    const int w    = tid >> 6;
    const int m    = lane & 15;
    const int q    = lane >> 4;
    const int rowBase = rU * 128 + w * 32;
    const int colBase = cU * 128;

    // Stage the whole 128 x 256B col tile: 8 uint4 per thread, coalesced.
    // Rows sr+16j => row&15 == sr, so swizzled chunk sc^sr is constant.
    {
        const int sr = tid >> 4;
        const int sc = tid & 15;
        const uint4* gsrc = (const uint4*)(zn + (size_t)(colBase + sr) * D_DIM) + sc;
        const int swc = sc ^ sr;
        uint4 regs[8];
        #pragma unroll
        for (int j = 0; j < 8; ++j) regs[j] = gsrc[j * 256];   // 16 rows apart
        #pragma unroll
        for (int j = 0; j < 8; ++j) lbuf[(sr + j * 16) * 16 + swc] = regs[j];
    }

    // A fragments: 2 row-sets x 4 K-steps, registers for the whole kernel
    bf16x8 afrag[2][4];
    #pragma unroll
    for (int h = 0; h < 2; ++h) {
        const short* ar = zn + (size_t)(rowBase + h * 16 + m) * D_DIM + q * 8;
        #pragma unroll
        for (int s = 0; s < 4; ++s) afrag[h][s] = *(const bf16x8*)(ar + s * 32);
    }

    __syncthreads();   // staging barrier

    float rsum[8] = {0.f, 0.f, 0.f, 0.f, 0.f, 0.f, 0.f, 0.f};
    const short* lb = (const short*)lbuf;

    #pragma unroll 2
    for (int ct = 0; ct < 8; ++ct) {
        f32x4 acc0 = {0.f, 0.f, 0.f, 0.f};
        f32x4 acc1 = {0.f, 0.f, 0.f, 0.f};
        #pragma unroll
        for (int s = 0; s < 4; ++s) {
            bf16x8 bfrag = *(const bf16x8*)(lb + (ct * 16 + m) * D_DIM
                                            + (((q + s * 4) ^ m) * 8));
            acc0 = __builtin_amdgcn_mfma_f32_16x16x32_bf16(afrag[0][s], bfrag, acc0, 0, 0, 0);
            acc1 = __builtin_amdgcn_mfma_f32_16x16x32_bf16(afrag[1][s], bfrag, acc1, 0, 0, 0);
        }
        const int tileCol = colBase + ct * 16;
        float e0[4], e1[4];
        #pragma unroll
        for (int r = 0; r < 4; ++r) { e0[r] = EXP2(acc0[r]); e1[r] = EXP2(acc1[r]); }
        // diagonal mask: wave-uniform branches; fire only when rU == cU
        if (tileCol == rowBase) {
            #pragma unroll
            for (int r = 0; r < 4; ++r) if (m == q * 4 + r) e0[r] = 0.f;
        }
        if (tileCol == rowBase + 16) {
            #pragma unroll
            for (int r = 0; r < 4; ++r) if (m == q * 4 + r) e1[r] = 0.f;
        }
        #pragma unroll
        for (int r = 0; r < 4; ++r) { rsum[r] += e0[r]; rsum[4 + r] += e1[r]; }
        // column partial for col (tileCol + m): sum this wave's 32 rows
        float cs = (e0[0] + e0[1]) + (e0[2] + e0[3])
                 + (e1[0] + e1[1]) + (e1[2] + e1[3]);
        cs += __shfl_xor(cs, 16, 64);
        cs += __shfl_xor(cs, 32, 64);
        if (q == 0) colpart[w][ct * 16 + m] = cs;
    }

    // row sums -> S[row]
    #pragma unroll
    for (int msk = 1; msk < 16; msk <<= 1) {
        #pragma unroll
        for (int r = 0; r < 8; ++r) rsum[r] += __shfl_xor(rsum[r], msk, 64);
    }
    if (m < 4) {
        atomicAdd(&S[rowBase + q * 4 + m],      rsum[m]);
        atomicAdd(&S[rowBase + 16 + q * 4 + m], rsum[4 + m]);
    }

    __syncthreads();   // colpart visibility across waves
    if (!isDiag && tid < 128) {
        float c = (colpart[0][tid] + colpart[1][tid])
                + (colpart[2][tid] + colpart[3][tid]);
        atomicAdd(&S[colBase + tid], c);
    }
}

// --- Kernel 3: out += (1/M^2) * sum_i [ log(S_i + exp(pos_i)) - pos_i ] ---
__global__ __launch_bounds__(1024) void loss_kernel(
    const float* __restrict__ S, const float* __restrict__ pos,
    float* __restrict__ out)
{
    const int i = blockIdx.x * 1024 + threadIdx.x;
    float p = pos[i & (N_ROWS - 1)];
    float v = __logf(S[i] + __expf(p)) - p;
    #pragma unroll
    for (int msk = 1; msk < 64; msk <<= 1) v += __shfl_xor(v, msk, 64);
    __shared__ float red[16];
    if ((threadIdx.x & 63) == 0) red[threadIdx.x >> 6] = v;
    __syncthreads();
    if (threadIdx.x == 0) {
        float t = 0.f;
        #pragma unroll
        for (int wv = 0; wv < 16; ++wv) t += red[wv];
        atomicAdd(out, t * (1.0f / ((float)M_ROWS * (float)M_ROWS)));
    }
}

extern "C" void kernel_launch(void* const* d_in, const int* in_sizes, int n_in,
                              void* d_out, int out_size, void* d_ws, size_t ws_size,
                              hipStream_t stream)
{
    const float* z1 = (const float*)d_in[0];
    const float* z2 = (const float*)d_in[1];
    float* out = (float*)d_out;

    char* wsp = (char*)d_ws;
    short* zn  = (short*)(wsp);                    // 2 MiB
    float* pos = (float*)(wsp + 2097152);          // 16 KiB
    float* S   = (float*)(wsp + 2097152 + 16384);  // 32 KiB

    prep_kernel<<<N_ROWS / 4, 256, 0, stream>>>(z1, z2, (ushort*)zn, pos, S, out);
    simsum_kernel<<<dim3(33, 64), 256, 0, stream>>>(zn, S);
    loss_kernel<<<M_ROWS / 1024, 1024, 0, stream>>>(S, pos, out);
}

// Round 12
// 77.611 us; speedup vs baseline: 2.6036x; 1.0008x over previous
//
#include <hip/hip_runtime.h>
#include <hip/hip_bf16.h>
#include <math.h>

#define N_ROWS 4096
#define D_DIM  128
#define M_ROWS 8192
#define INV_T  10.0f
// sqrt(10/ln2): zn scaled so Gram(zn) = 10*log2(e)*cos  =>  exp2(Gram) = e^(10*cos)
#define BF_SCALE 3.79828218f

#if __has_builtin(__builtin_amdgcn_exp2f)
#define EXP2(x) __builtin_amdgcn_exp2f(x)   // bare v_exp_f32, no OCML fixup
#else
#define EXP2(x) exp2f(x)
#endif

typedef __attribute__((ext_vector_type(8))) short bf16x8;
typedef __attribute__((ext_vector_type(4))) float f32x4;

// --- Kernel 1: fused normalize (scaled bf16) + pos + zero S + zero out ---
__global__ __launch_bounds__(256) void prep_kernel(
    const float* __restrict__ z1, const float* __restrict__ z2,
    ushort* __restrict__ zn, float* __restrict__ pos,
    float* __restrict__ S, float* __restrict__ out)
{
    if (blockIdx.x < 32) S[blockIdx.x * 256 + threadIdx.x] = 0.f;
    if (blockIdx.x == 32 && threadIdx.x == 0) out[0] = 0.f;

    const int i    = blockIdx.x * 4 + (threadIdx.x >> 6);
    const int lane = threadIdx.x & 63;
    float2 a = ((const float2*)(z1 + (size_t)i * D_DIM))[lane];
    float2 b = ((const float2*)(z2 + (size_t)i * D_DIM))[lane];
    float s11 = a.x * a.x + a.y * a.y;
    float s22 = b.x * b.x + b.y * b.y;
    float s12 = a.x * b.x + a.y * b.y;
    #pragma unroll
    for (int m = 1; m < 64; m <<= 1) {
        s11 += __shfl_xor(s11, m, 64);
        s22 += __shfl_xor(s22, m, 64);
        s12 += __shfl_xor(s12, m, 64);
    }
    float inv1 = 1.0f / fmaxf(sqrtf(s11), 1e-8f);
    float inv2 = 1.0f / fmaxf(sqrtf(s22), 1e-8f);
    if (lane == 0) pos[i] = 2.0f * INV_T * s12 * inv1 * inv2;
    const float sa = inv1 * BF_SCALE, sb = inv2 * BF_SCALE;
    __hip_bfloat16 h;
    ushort2 oa, ob;
    h = __float2bfloat16(a.x * sa); oa.x = *(const ushort*)&h;
    h = __float2bfloat16(a.y * sa); oa.y = *(const ushort*)&h;
    h = __float2bfloat16(b.x * sb); ob.x = *(const ushort*)&h;
    h = __float2bfloat16(b.y * sb); ob.y = *(const ushort*)&h;
    ((ushort2*)zn)[(size_t)i * 64 + lane] = oa;
    ((ushort2*)zn)[(size_t)(i + N_ROWS) * 64 + lane] = ob;
}

// --- Kernel 2: symmetric simsum. E = exp(sim) is symmetric: only the upper
// triangle of 128x128 unit tiles is computed. Wrapped-diagonal grid: (bx,rU)
// in 33x64, cU=(rU+bx)&63, bx==32 only for rU<32 => each unordered pair once
// (2080 blocks). One-shot staging (whole 128-col tile -> 32 KiB LDS,
// XOR-swizzled), ONE barrier total. Column sums go straight to S[col] via
// per-wave atomics (no colpart LDS, no second barrier) => LDS exactly 32 KiB
// => 5 blocks/CU. NO device fences anywhere (R10 lesson).
__global__ __launch_bounds__(256) void simsum_kernel(
    const short* __restrict__ zn, float* __restrict__ S)
{
    const int bx = blockIdx.x;          // 0..32
    const int rU = blockIdx.y;          // 0..63
    if (bx == 32 && rU >= 32) return;   // distance-32 pairs covered once
    const int cU = (rU + bx) & 63;
    const bool isDiag = (bx == 0);

    __shared__ uint4 lbuf[128 * 16];    // 32 KiB exactly: [row][chunk]

    const int tid  = threadIdx.x;
    const int lane = tid & 63;
    const int w    = tid >> 6;
    const int m    = lane & 15;
    const int q    = lane >> 4;
    const int rowBase = rU * 128 + w * 32;
    const int colBase = cU * 128;

    // Stage the whole 128 x 256B col tile: 8 uint4 per thread, coalesced.
    // Rows sr+16j => row&15 == sr, so swizzled chunk sc^sr is constant.
    {
        const int sr = tid >> 4;
        const int sc = tid & 15;
        const uint4* gsrc = (const uint4*)(zn + (size_t)(colBase + sr) * D_DIM) + sc;
        const int swc = sc ^ sr;
        uint4 regs[8];
        #pragma unroll
        for (int j = 0; j < 8; ++j) regs[j] = gsrc[j * 256];   // 16 rows apart
        #pragma unroll
        for (int j = 0; j < 8; ++j) lbuf[(sr + j * 16) * 16 + swc] = regs[j];
    }

    // A fragments: 2 row-sets x 4 K-steps, registers for the whole kernel
    bf16x8 afrag[2][4];
    #pragma unroll
    for (int h = 0; h < 2; ++h) {
        const short* ar = zn + (size_t)(rowBase + h * 16 + m) * D_DIM + q * 8;
        #pragma unroll
        for (int s = 0; s < 4; ++s) afrag[h][s] = *(const bf16x8*)(ar + s * 32);
    }

    __syncthreads();   // the ONLY barrier in this kernel

    float rsum[8] = {0.f, 0.f, 0.f, 0.f, 0.f, 0.f, 0.f, 0.f};
    const short* lb = (const short*)lbuf;

    #pragma unroll 2
    for (int ct = 0; ct < 8; ++ct) {
        f32x4 acc0 = {0.f, 0.f, 0.f, 0.f};
        f32x4 acc1 = {0.f, 0.f, 0.f, 0.f};
        #pragma unroll
        for (int s = 0; s < 4; ++s) {
            bf16x8 bfrag = *(const bf16x8*)(lb + (ct * 16 + m) * D_DIM
                                            + (((q + s * 4) ^ m) * 8));
            acc0 = __builtin_amdgcn_mfma_f32_16x16x32_bf16(afrag[0][s], bfrag, acc0, 0, 0, 0);
            acc1 = __builtin_amdgcn_mfma_f32_16x16x32_bf16(afrag[1][s], bfrag, acc1, 0, 0, 0);
        }
        const int tileCol = colBase + ct * 16;
        float e0[4], e1[4];
        #pragma unroll
        for (int r = 0; r < 4; ++r) { e0[r] = EXP2(acc0[r]); e1[r] = EXP2(acc1[r]); }
        // diagonal mask: wave-uniform branches; fire only when rU == cU
        if (tileCol == rowBase) {
            #pragma unroll
            for (int r = 0; r < 4; ++r) if (m == q * 4 + r) e0[r] = 0.f;
        }
        if (tileCol == rowBase + 16) {
            #pragma unroll
            for (int r = 0; r < 4; ++r) if (m == q * 4 + r) e1[r] = 0.f;
        }
        #pragma unroll
        for (int r = 0; r < 4; ++r) { rsum[r] += e0[r]; rsum[4 + r] += e1[r]; }
        // column partial for col (tileCol + m) over this wave's 32 rows:
        // straight to S via atomics (fire-and-forget, no dependents)
        if (!isDiag) {
            float cs = (e0[0] + e0[1]) + (e0[2] + e0[3])
                     + (e1[0] + e1[1]) + (e1[2] + e1[3]);
            cs += __shfl_xor(cs, 16, 64);
            cs += __shfl_xor(cs, 32, 64);
            if (q == 0) atomicAdd(&S[tileCol + m], cs);
        }
    }

    // row sums -> S[row]
    #pragma unroll
    for (int msk = 1; msk < 16; msk <<= 1) {
        #pragma unroll
        for (int r = 0; r < 8; ++r) rsum[r] += __shfl_xor(rsum[r], msk, 64);
    }
    if (m < 4) {
        atomicAdd(&S[rowBase + q * 4 + m],      rsum[m]);
        atomicAdd(&S[rowBase + 16 + q * 4 + m], rsum[4 + m]);
    }
}

// --- Kernel 3: out += (1/M^2) * sum_i [ log(S_i + exp(pos_i)) - pos_i ] ---
__global__ __launch_bounds__(1024) void loss_kernel(
    const float* __restrict__ S, const float* __restrict__ pos,
    float* __restrict__ out)
{
    const int i = blockIdx.x * 1024 + threadIdx.x;
    float p = pos[i & (N_ROWS - 1)];
    float v = __logf(S[i] + __expf(p)) - p;
    #pragma unroll
    for (int msk = 1; msk < 64; msk <<= 1) v += __shfl_xor(v, msk, 64);
    __shared__ float red[16];
    if ((threadIdx.x & 63) == 0) red[threadIdx.x >> 6] = v;
    __syncthreads();
    if (threadIdx.x == 0) {
        float t = 0.f;
        #pragma unroll
        for (int wv = 0; wv < 16; ++wv) t += red[wv];
        atomicAdd(out, t * (1.0f / ((float)M_ROWS * (float)M_ROWS)));
    }
}

extern "C" void kernel_launch(void* const* d_in, const int* in_sizes, int n_in,
                              void* d_out, int out_size, void* d_ws, size_t ws_size,
                              hipStream_t stream)
{
    const float* z1 = (const float*)d_in[0];
    const float* z2 = (const float*)d_in[1];
    float* out = (float*)d_out;

    char* wsp = (char*)d_ws;
    short* zn  = (short*)(wsp);                    // 2 MiB
    float* pos = (float*)(wsp + 2097152);          // 16 KiB
    float* S   = (float*)(wsp + 2097152 + 16384);  // 32 KiB

    prep_kernel<<<N_ROWS / 4, 256, 0, stream>>>(z1, z2, (ushort*)zn, pos, S, out);
    simsum_kernel<<<dim3(33, 64), 256, 0, stream>>>(zn, S);
    loss_kernel<<<M_ROWS / 1024, 1024, 0, stream>>>(S, pos, out);
}